// Round 18
// baseline (1776.339 us; speedup 1.0000x reference)
//
#include <hip/hip_runtime.h>
#include <hip/hip_bf16.h>
#include <math.h>

#define NL 6
#define DM 272
#define DS 64
#define DI 544
#define DTR 17
#define NSC 4
#define BB 4
#define LL 2048
#define MTOK (BB*LL)
#define TCH 128
#define CH  16
#define DQ  (DI/4)   // 136

typedef __attribute__((ext_vector_type(8))) short bf16x8;
typedef __attribute__((ext_vector_type(4))) float f32x4;
typedef __attribute__((ext_vector_type(2))) float f32x2;

__device__ __forceinline__ float sigmoidf_(float x){ return 1.0f/(1.0f+__expf(-x)); }
__device__ __forceinline__ unsigned short f2bfu(float x){
    union { __hip_bfloat16 h; unsigned short u; } c; c.h = __float2bfloat16(x); return c.u;
}
__device__ __forceinline__ float bfu2f(unsigned short u){ return __uint_as_float(((unsigned)u)<<16); }
__device__ __forceinline__ float bclo(unsigned int bc){ return __uint_as_float(bc << 16); }
__device__ __forceinline__ float bchi(unsigned int bc){ return __uint_as_float(bc & 0xffff0000u); }
__device__ __forceinline__ float exp2x(float x){ float r; asm("v_exp_f32 %0, %1" : "=v"(r) : "v"(x)); return r; }
__device__ __forceinline__ float log2x(float x){ float r; asm("v_log_f32 %0, %1" : "=v"(r) : "v"(x)); return r; }
__device__ __forceinline__ float softplus_(float s){
    float sp = 0.6931471806f * log2x(1.0f + exp2x(s * 1.44269504f));
    return (s > 20.f) ? s : sp;
}
// CDNA packed f32 (VOP3P): 2 f32 ops in one instruction on VGPR pairs
__device__ __forceinline__ f32x2 pk_mul2(f32x2 a, f32x2 b){
    f32x2 d; asm("v_pk_mul_f32 %0, %1, %2" : "=v"(d) : "v"(a), "v"(b)); return d;
}
__device__ __forceinline__ f32x2 pk_fma2(f32x2 a, f32x2 b, f32x2 c){
    f32x2 d; asm("v_pk_fma_f32 %0, %1, %2, %3" : "=v"(d) : "v"(a), "v"(b), "v"(c)); return d;
}

#define DPPADD(x, ctrl) x += __int_as_float(__builtin_amdgcn_update_dpp(0, __float_as_int(x), ctrl, 0xf, 0xf, true))
__device__ __forceinline__ float wsum64(float x){
    DPPADD(x, 0x111); DPPADD(x, 0x112); DPPADD(x, 0x114); DPPADD(x, 0x118);
    DPPADD(x, 0x142); DPPADD(x, 0x143);
    return x;
}

// ---------------- LayerNorm: one wave per token, bf16 output ----------------
__global__ __launch_bounds__(256) void ln_kernel(const float* __restrict__ X,
                          const float* __restrict__ w,
                          const float* __restrict__ b,
                          unsigned short* __restrict__ Hb)
{
    int wave = threadIdx.x >> 6;
    int lane = threadIdx.x & 63;
    int tok = blockIdx.x*4 + wave;
    const float* xr = X + (size_t)tok*DM;
    float v[5];
    float s=0.f, ss=0.f;
    #pragma unroll
    for (int j=0;j<5;++j){
        int idx = lane + j*64;
        float x = (idx < DM) ? xr[idx] : 0.f;
        v[j]=x; s+=x; ss+=x*x;
    }
    #pragma unroll
    for (int off=1; off<64; off<<=1){ s += __shfl_xor(s,off); ss += __shfl_xor(ss,off); }
    float mu  = s * (1.0f/DM);
    float var = ss*(1.0f/DM) - mu*mu;
    float inv = 1.0f/sqrtf(var + 1e-5f);
    unsigned short* hr = Hb + (size_t)tok*DM;
    #pragma unroll
    for (int j=0;j<5;++j){
        int idx = lane + j*64;
        if (idx<DM) hr[idx] = f2bfu((v[j]-mu)*inv*w[idx] + b[idx]);
    }
}

// ======= bf16 MFMA GEMM. OMODE: 0=f32 out, 1=bf16 out, 2=x_proj split (DTb f32 + BCb bf16-pair) =======
template<int OMODE, bool RESID>
__global__ __launch_bounds__(256) void gmfma(const unsigned short* __restrict__ A, int lda,
                     const unsigned short* __restrict__ W, int ldw,
                     void* __restrict__ Cv, int ldc,
                     const float* __restrict__ R, int ldr,
                     void* __restrict__ aux,
                     int N, int K)
{
    __shared__ unsigned short As[128*40];
    __shared__ unsigned short Bs[128*40];
    int bm = blockIdx.x*128, bn = blockIdx.y*128;
    int tid = threadIdx.x;
    int lane = tid & 63, wave = tid >> 6;
    int wm = wave >> 1, wn = wave & 1;
    f32x4 acc[4][4] = {};
    int r16 = lane & 15, kg = (lane >> 4) * 8;
    for (int k0=0; k0<K; k0+=32){
        #pragma unroll
        for (int it=0; it<2; ++it){
            int cid = tid + it*256;
            int row = cid >> 2, kq = (cid & 3)*8;
            int kk = k0 + kq;
            uint4 za = make_uint4(0,0,0,0);
            if (kk < K) za = *(const uint4*)(A + (size_t)(bm+row)*lda + kk);
            *(uint4*)&As[row*40 + kq] = za;
            uint4 zb = make_uint4(0,0,0,0);
            int wr = bn + row;
            if (wr < N && kk < K) zb = *(const uint4*)(W + (size_t)wr*ldw + kk);
            *(uint4*)&Bs[row*40 + kq] = zb;
        }
        __syncthreads();
        bf16x8 af[4], bfr[4];
        #pragma unroll
        for (int mi=0; mi<4; ++mi)
            af[mi] = *(bf16x8*)&As[(wm*64 + mi*16 + r16)*40 + kg];
        #pragma unroll
        for (int ni=0; ni<4; ++ni)
            bfr[ni] = *(bf16x8*)&Bs[(wn*64 + ni*16 + r16)*40 + kg];
        #pragma unroll
        for (int mi=0; mi<4; ++mi)
            #pragma unroll
            for (int ni=0; ni<4; ++ni)
                acc[mi][ni] = __builtin_amdgcn_mfma_f32_16x16x32_bf16(af[mi], bfr[ni], acc[mi][ni], 0, 0, 0);
        __syncthreads();
    }
    int rowt = (lane >> 4)*4, colt = lane & 15;
    #pragma unroll
    for (int mi=0; mi<4; ++mi){
        #pragma unroll
        for (int ni=0; ni<4; ++ni){
            int col = bn + wn*64 + ni*16 + colt;
            if (col < N){
                #pragma unroll
                for (int j=0; j<4; ++j){
                    int row = bm + wm*64 + mi*16 + rowt + j;
                    float v = acc[mi][ni][j];
                    if (RESID) v += R[(size_t)row*ldr + col];
                    if (OMODE == 0)
                        ((float*)Cv)[(size_t)row*ldc + col] = v;
                    else if (OMODE == 1)
                        ((unsigned short*)Cv)[(size_t)row*ldc + col] = f2bfu(v);
                    else {
                        if (col < DTR)
                            ((float*)Cv)[(size_t)row*DTR + col] = v;
                        else if (col < DTR + DS)
                            ((unsigned short*)aux)[((size_t)row*DS + col - DTR)*2] = f2bfu(v);
                        else
                            ((unsigned short*)aux)[((size_t)row*DS + col - DTR - DS)*2 + 1] = f2bfu(v);
                    }
                }
            }
        }
    }
}

// ------- conv+SiLU+gate (bf16 in): outputs UGt uint32 {lo:u, hi:g} [d][t] + XCb bf16 [tok][d] -------
__global__ __launch_bounds__(256) void conv_t2_kernel(const unsigned short* __restrict__ XZb,
                                 const float* __restrict__ cw,
                                 const float* __restrict__ cb,
                                 unsigned int* __restrict__ UGt,
                                 unsigned short* __restrict__ XCb)
{
    __shared__ float xi[67][69];
    __shared__ float zz[64][69];
    int bid = blockIdx.x;
    int b  = bid >> 8;
    int rem = bid & 255;
    int t0 = (rem >> 3)*64;
    int d0 = (rem & 7)*68;
    int tid = threadIdx.x;
    for (int li = tid; li < 67*17; li += 256){
        int row = li / 17, q = li - row*17;
        int tg = t0 - 3 + row;
        float4 v = make_float4(0.f,0.f,0.f,0.f);
        if (tg >= 0){
            ushort4 u4 = *(const ushort4*)(XZb + ((size_t)b*LL + tg)*(2*DI) + d0 + q*4);
            v.x = bfu2f(u4.x); v.y = bfu2f(u4.y); v.z = bfu2f(u4.z); v.w = bfu2f(u4.w);
        }
        xi[row][q*4+0]=v.x; xi[row][q*4+1]=v.y; xi[row][q*4+2]=v.z; xi[row][q*4+3]=v.w;
    }
    for (int li = tid; li < 64*17; li += 256){
        int row = li / 17, q = li - row*17;
        ushort4 u4 = *(const ushort4*)(XZb + ((size_t)b*LL + t0 + row)*(2*DI) + DI + d0 + q*4);
        zz[row][q*4+0]=bfu2f(u4.x); zz[row][q*4+1]=bfu2f(u4.y);
        zz[row][q*4+2]=bfu2f(u4.z); zz[row][q*4+3]=bfu2f(u4.w);
    }
    __syncthreads();
    int t = tid & 63;
    int dw = tid >> 6;
    float xcreg[17];
    #pragma unroll
    for (int i=0; i<17; ++i){
        int dl = dw + i*4;
        int d = d0 + dl;
        const float* cwd = cw + d*4;
        float acc = cb[d];
        #pragma unroll
        for (int k=0;k<4;++k) acc = fmaf(xi[t+k][dl], cwd[k], acc);
        float xc = acc * sigmoidf_(acc);
        float z  = zz[t][dl];
        size_t o = ((size_t)b*DI + d)*LL + t0 + t;
        float g = z * sigmoidf_(z);
        UGt[o] = (unsigned int)f2bfu(xc) | ((unsigned int)f2bfu(g) << 16);
        xcreg[i] = xc;
    }
    __syncthreads();
    #pragma unroll
    for (int i=0; i<17; ++i) zz[t][dw + i*4] = xcreg[i];
    __syncthreads();
    for (int li = tid; li < 64*17; li += 256){
        int row = li / 17, q = li - row*17;
        ushort4 v;
        v.x = f2bfu(zz[row][q*4+0]); v.y = f2bfu(zz[row][q*4+1]);
        v.z = f2bfu(zz[row][q*4+2]); v.w = f2bfu(zz[row][q*4+3]);
        *(ushort4*)&XCb[((size_t)b*LL + t0 + row)*DI + d0 + q*4] = v;
    }
}

// ======= chunked scan, pass A: 4 ch/wave (2 packed pairs), fused dt, BCb dword loads =======
__global__ __launch_bounds__(256) void scan_a(const unsigned int* __restrict__ UGt,
                       const float* __restrict__ DTb,
                       const unsigned int* __restrict__ BCb,
                       const float* __restrict__ Wdt,
                       const float* __restrict__ bdt,
                       const float* __restrict__ A_log,
                       float* __restrict__ Q,
                       float* __restrict__ S,
                       unsigned short* __restrict__ DELtb)
{
    __shared__ __align__(16) f32x4 dlb[4][2][64];   // [wave][pair(ch01,ch23)][step]={dl.lo,dl.hi,du.lo,du.hi}
    int tid = threadIdx.x;
    int wave = tid >> 6, lane = tid & 63;
    f32x4 (*DbW)[64] = dlb[wave];
    int wid = blockIdx.x*4 + wave;            // (b, c, dd) dd fastest
    int dd = wid % DQ;
    int c  = (wid / DQ) % CH;
    int b  = wid / (DQ*CH);
    int d0 = dd, d1 = dd+DQ, d2 = dd+2*DQ, d3 = dd+3*DQ;
    const float L2E = 1.44269504f;
    f32x2 Av01, Av23;
    Av01.x = -__expf(A_log[d0*DS + lane]) * L2E;
    Av01.y = -__expf(A_log[d1*DS + lane]) * L2E;
    Av23.x = -__expf(A_log[d2*DS + lane]) * L2E;
    Av23.y = -__expf(A_log[d3*DS + lane]) * L2E;
    const float* wd0 = Wdt + d0*DTR;
    const float* wd1 = Wdt + d1*DTR;
    const float* wd2 = Wdt + d2*DTR;
    const float* wd3 = Wdt + d3*DTR;
    f32x2 h01 = {0.f,0.f}, h23 = {0.f,0.f};
    float ds0=0.f,ds1=0.f,ds2=0.f,ds3=0.f;
    size_t tokBase = (size_t)b*LL + (size_t)c*TCH;
    size_t rb0 = ((size_t)b*DI + d0)*LL + c*TCH;
    size_t rb1 = ((size_t)b*DI + d1)*LL + c*TCH;
    size_t rb2 = ((size_t)b*DI + d2)*LL + c*TCH;
    size_t rb3 = ((size_t)b*DI + d3)*LL + c*TCH;
    for (int blk=0; blk<TCH/64; ++blk){
        const float* dp = DTb + (tokBase + blk*64 + lane)*DTR;
        float s0=bdt[d0], s1=bdt[d1], s2=bdt[d2], s3=bdt[d3];
        #pragma unroll
        for (int r=0;r<17;++r){
            float d = dp[r];
            s0 = fmaf(d, wd0[r], s0);
            s1 = fmaf(d, wd1[r], s1);
            s2 = fmaf(d, wd2[r], s2);
            s3 = fmaf(d, wd3[r], s3);
        }
        float dl0 = softplus_(s0), dl1 = softplus_(s1);
        float dl2 = softplus_(s2), dl3 = softplus_(s3);
        size_t o0 = rb0 + blk*64 + lane, o1 = rb1 + blk*64 + lane;
        size_t o2 = rb2 + blk*64 + lane, o3 = rb3 + blk*64 + lane;
        DELtb[o0] = f2bfu(dl0); DELtb[o1] = f2bfu(dl1);
        DELtb[o2] = f2bfu(dl2); DELtb[o3] = f2bfu(dl3);
        float du0 = dl0*bfu2f((unsigned short)UGt[o0]);
        float du1 = dl1*bfu2f((unsigned short)UGt[o1]);
        float du2 = dl2*bfu2f((unsigned short)UGt[o2]);
        float du3 = dl3*bfu2f((unsigned short)UGt[o3]);
        ds0 += dl0; ds1 += dl1; ds2 += dl2; ds3 += dl3;
        DbW[0][lane] = (f32x4){dl0, dl1, du0, du1};
        DbW[1][lane] = (f32x4){dl2, dl3, du2, du3};
        const unsigned int* pbc = BCb + (tokBase + blk*64)*DS;
        #pragma unroll 1
        for (int g=0; g<8; ++g){
            #pragma unroll
            for (int i=0; i<8; ++i){
                f32x4 a01 = DbW[0][g*8+i];     // uniform-address b128 broadcast
                f32x4 a23 = DbW[1][g*8+i];
                float Bv = bclo(pbc[lane]);
                f32x2 t01 = pk_mul2(__builtin_shufflevector(a01,a01,0,1), Av01);
                f32x2 t23 = pk_mul2(__builtin_shufflevector(a23,a23,0,1), Av23);
                f32x2 e01, e23;
                e01.x = exp2x(t01.x); e01.y = exp2x(t01.y);
                e23.x = exp2x(t23.x); e23.y = exp2x(t23.y);
                f32x2 dub01, dub23;
                dub01.x = a01.z*Bv; dub01.y = a01.w*Bv;
                dub23.x = a23.z*Bv; dub23.y = a23.w*Bv;
                h01 = pk_fma2(e01, h01, dub01);
                h23 = pk_fma2(e23, h23, dub23);
                pbc += DS;
            }
        }
    }
    size_t q0i = ((size_t)b*DI + d0)*CH + c, q1i = ((size_t)b*DI + d1)*CH + c;
    size_t q2i = ((size_t)b*DI + d2)*CH + c, q3i = ((size_t)b*DI + d3)*CH + c;
    Q[q0i*64 + lane] = h01.x; Q[q1i*64 + lane] = h01.y;
    Q[q2i*64 + lane] = h23.x; Q[q3i*64 + lane] = h23.y;
    float s0w = wsum64(ds0), s1w = wsum64(ds1), s2w = wsum64(ds2), s3w = wsum64(ds3);
    if (lane == 63){ S[q0i]=s0w; S[q1i]=s1w; S[q2i]=s2w; S[q3i]=s3w; }
}

// ======= chunked scan, pass C: 2 ch packed, interleaved P, b64 writes, Yst-staged out =======
__global__ __launch_bounds__(256) void scan_c(const unsigned int* __restrict__ UGt,
                       const unsigned short* __restrict__ DELtb,
                       const unsigned int* __restrict__ BCb,
                       const float* __restrict__ A_log,
                       const float* __restrict__ Dskip,
                       const float* __restrict__ Q,
                       const float* __restrict__ S,
                       unsigned short* __restrict__ Yb)
{
    __shared__ __align__(16) f32x2 Pr[4][4][66];    // [wave][step][state] interleaved {ch0,ch1}
    __shared__ float Ypark[4][2][4];
    __shared__ __align__(16) f32x4 dlb[4][64];      // [wave][step]={dl0,dl1,du0,du1}
    __shared__ unsigned short Yst[64][12];
    int tid = threadIdx.x;
    int wave = tid >> 6, lane = tid & 63;
    f32x2 (*PrW)[66] = Pr[wave];
    float* Yp0 = Ypark[wave][0];
    float* Yp1 = Ypark[wave][1];
    f32x4* DbW = dlb[wave];
    int wid = blockIdx.x*4 + wave;            // 4 waves share (b,c); dd consecutive
    int dd = wid % (DI/2);
    int c  = (wid / (DI/2)) % CH;
    int b  = wid / ((DI/2)*CH);
    int d0 = dd, d1 = dd + DI/2;
    int wid0 = blockIdx.x*4;
    int dd0b = wid0 % (DI/2);
    int cB = (wid0 / (DI/2)) % CH;
    int bB = wid0 / ((DI/2)*CH);
    const float L2E = 1.44269504f;
    f32x2 Av;
    Av.x = -__expf(A_log[d0*DS + lane]) * L2E;
    Av.y = -__expf(A_log[d1*DS + lane]) * L2E;
    float Dd0 = Dskip[d0], Dd1 = Dskip[d1];
    size_t q0 = ((size_t)b*DI + d0)*CH, q1 = ((size_t)b*DI + d1)*CH;
    float h0=0.f, h1=0.f;
    for (int j=0; j<c; ++j){
        h0 = fmaf(exp2x(Av.x*S[q0+j]), h0, Q[(q0+j)*64 + lane]);
        h1 = fmaf(exp2x(Av.y*S[q1+j]), h1, Q[(q1+j)*64 + lane]);
    }
    f32x2 h; h.x = h0; h.y = h1;
    size_t tokBase = (size_t)b*LL + (size_t)c*TCH;
    size_t rb0 = ((size_t)b*DI + d0)*LL + c*TCH;
    size_t rb1 = ((size_t)b*DI + d1)*LL + c*TCH;
    int fr = lane >> 4, fq = (lane & 15)*4;
    for (int blk=0; blk<TCH/64; ++blk){
        size_t o0 = rb0 + blk*64 + lane, o1 = rb1 + blk*64 + lane;
        float dl0 = bfu2f(DELtb[o0]), dl1 = bfu2f(DELtb[o1]);
        unsigned int ug0 = UGt[o0], ug1 = UGt[o1];
        float ul0 = bfu2f((unsigned short)ug0), ul1 = bfu2f((unsigned short)ug1);
        float gl0 = bfu2f((unsigned short)(ug0 >> 16)), gl1 = bfu2f((unsigned short)(ug1 >> 16));
        DbW[lane] = (f32x4){dl0, dl1, dl0*ul0, dl1*ul1};
        float y0=0.f, y1=0.f;
        const unsigned int* pbc = BCb + (tokBase + blk*64)*DS;
        #pragma unroll 1
        for (int f=0; f<16; ++f){
            #pragma unroll
            for (int i=0; i<4; ++i){
                f32x4 dd4 = DbW[f*4 + i];      // uniform-address b128 broadcast
                unsigned int bc = pbc[lane];
                float Bv = bclo(bc);
                float Cv = bchi(bc);
                f32x2 t = pk_mul2(__builtin_shufflevector(dd4, dd4, 0, 1), Av);
                f32x2 e; e.x = exp2x(t.x); e.y = exp2x(t.y);
                f32x2 dub; dub.x = dd4.z*Bv; dub.y = dd4.w*Bv;
                h = pk_fma2(e, h, dub);
                f32x2 hc; hc.x = h.x*Cv; hc.y = h.y*Cv;
                PrW[i][lane] = hc;             // single ds_write_b64
                pbc += DS;
            }
            f32x4 qa = *(const f32x4*)&PrW[fr][fq];
            f32x4 qb = *(const f32x4*)&PrW[fr][fq+2];
            float s0f = (qa.x+qa.z)+(qb.x+qb.z);
            float s1f = (qa.y+qa.w)+(qb.y+qb.w);
            DPPADD(s0f,0x111); DPPADD(s0f,0x112); DPPADD(s0f,0x114); DPPADD(s0f,0x118);
            DPPADD(s1f,0x111); DPPADD(s1f,0x112); DPPADD(s1f,0x114); DPPADD(s1f,0x118);
            if ((lane & 15) == 15){ Yp0[fr] = s0f; Yp1[fr] = s1f; }
            float g0 = Yp0[lane & 3];
            float g1 = Yp1[lane & 3];
            if ((lane >> 2) == f){ y0 = g0; y1 = g1; }
        }
        Yst[lane][wave]     = f2bfu((y0 + ul0*Dd0)*gl0);
        Yst[lane][4 + wave] = f2bfu((y1 + ul1*Dd1)*gl1);
        __syncthreads();
        if (tid < 128){
            int row = tid & 63, grp = tid >> 6;
            ushort4 v = *(const ushort4*)&Yst[row][grp*4];
            size_t trow = (size_t)bB*LL + (size_t)cB*TCH + blk*64 + row;
            *(ushort4*)&Yb[trow*DI + dd0b + grp*(DI/2)] = v;
        }
        __syncthreads();
    }
}

// ------- weight f32 -> bf16 convert -------
__global__ __launch_bounds__(256) void wconv_kernel(const float* __restrict__ src,
                            unsigned short* __restrict__ dst,
                            int total, int kin, int kout)
{
    int idx = blockIdx.x*256 + threadIdx.x;
    if (idx >= total) return;
    int r = idx / kout, c = idx - r*kout;
    float v = (c < kin) ? src[(size_t)r*kin + c] : 0.f;
    dst[idx] = f2bfu(v);
}

// ------- head: two-stage mean-pool + regression -------
__global__ __launch_bounds__(256) void head1_kernel(const float* __restrict__ X,
                             float* __restrict__ Pt)
{
    int b = blockIdx.x >> 6, c = blockIdx.x & 63;
    int tid = threadIdx.x;
    for (int dm = tid; dm < DM; dm += 256){
        float s = 0.f;
        const float* base = X + ((size_t)b*LL + c*32)*DM + dm;
        #pragma unroll 8
        for (int tt=0; tt<32; ++tt) s += base[(size_t)tt*DM];
        Pt[(size_t)(b*64 + c)*DM + dm] = s;
    }
}

__global__ __launch_bounds__(256) void head2_kernel(const float* __restrict__ Pt,
                             const float* __restrict__ reg_w,
                             const float* __restrict__ reg_b,
                             float* __restrict__ out)
{
    __shared__ float feat[DM];
    int b = blockIdx.x, tid = threadIdx.x;
    for (int dm = tid; dm < DM; dm += 256){
        float s = 0.f;
        for (int c=0; c<64; ++c) s += Pt[(size_t)(b*64 + c)*DM + dm];
        float f = s * (1.0f/LL);
        feat[dm] = f;
        out[16 + b*DM + dm] = f;
    }
    __syncthreads();
    if (tid < NSC){
        float s = reg_b[tid];
        const float* wr = reg_w + tid*DM;
        for (int k=0;k<DM;++k) s = fmaf(feat[k], wr[k], s);
        out[b*NSC + tid] = s;
    }
}

extern "C" void kernel_launch(void* const* d_in, const int* in_sizes, int n_in,
                              void* d_out, int out_size, void* d_ws, size_t ws_size,
                              hipStream_t stream)
{
    const float* x_in  = (const float*)d_in[0];
    const float* ln_w  = (const float*)d_in[1];
    const float* ln_b  = (const float*)d_in[2];
    const float* Wi    = (const float*)d_in[3];
    const float* cw    = (const float*)d_in[4];
    const float* cb    = (const float*)d_in[5];
    const float* Wx    = (const float*)d_in[6];
    const float* Wdt   = (const float*)d_in[7];
    const float* bdt   = (const float*)d_in[8];
    const float* A_log = (const float*)d_in[9];
    const float* Dd    = (const float*)d_in[10];
    const float* Wo    = (const float*)d_in[11];
    const float* regw  = (const float*)d_in[12];
    const float* regb  = (const float*)d_in[13];
    float* out = (float*)d_out;

    char* base = (char*)d_ws;
    auto carve = [&](size_t bytes) -> char* {
        char* p = base; base += (bytes + 255) & ~(size_t)255; return p;
    };
    unsigned short* XZb   = (unsigned short*)carve((size_t)MTOK*1088*2);
    unsigned int*   UGt   = (unsigned int*)carve((size_t)MTOK*544*4);
    unsigned short* DELtb = (unsigned short*)carve((size_t)MTOK*544*2);
    float*          DTb   = (float*)carve((size_t)MTOK*DTR*4);
    unsigned int*   BCb   = (unsigned int*)carve((size_t)MTOK*DS*4);
    float*          Xb    = (float*)carve((size_t)MTOK*272*4);
    unsigned short* Yb    = (unsigned short*)carve((size_t)MTOK*544*2);
    char*           SCR   = carve((size_t)MTOK*272*4);   // Hb / XCb / Q / Pt overlay
    float*          Sbuf  = (float*)carve((size_t)BB*DI*CH*4);
    unsigned short* WiB   = (unsigned short*)carve((size_t)NL*1088*DM*2);
    unsigned short* WxB   = (unsigned short*)carve((size_t)NL*145*DI*2);
    unsigned short* WoB   = (unsigned short*)carve((size_t)NL*272*DI*2);

    unsigned short* Hb  = (unsigned short*)SCR;
    unsigned short* XCb = (unsigned short*)SCR;
    float*          Q   = (float*)SCR;
    float*          Pt  = (float*)SCR;

    (void)hipMemcpyAsync(Xb, x_in, sizeof(float)*(size_t)MTOK*DM, hipMemcpyDeviceToDevice, stream);

    wconv_kernel<<<(NL*1088*DM + 255)/256, 256, 0, stream>>>(Wi, WiB, NL*1088*DM, DM, DM);
    wconv_kernel<<<(NL*145*DI + 255)/256, 256, 0, stream>>>(Wx, WxB, NL*145*DI, DI, DI);
    wconv_kernel<<<(NL*272*DI + 255)/256, 256, 0, stream>>>(Wo, WoB, NL*272*DI, DI, DI);

    for (int l=0; l<NL; ++l){
        ln_kernel<<<MTOK/4, 256, 0, stream>>>(Xb, ln_w + l*DM, ln_b + l*DM, Hb);
        gmfma<1,false><<<dim3(MTOK/128, (2*DI+127)/128), 256, 0, stream>>>(
            Hb, DM, WiB + (size_t)l*2*DI*DM, DM, XZb, 2*DI, nullptr, 0, nullptr, 2*DI, DM);
        conv_t2_kernel<<<BB*256, 256, 0, stream>>>(XZb, cw + l*DI*4, cb + l*DI, UGt, XCb);
        gmfma<2,false><<<dim3(MTOK/128, 2), 256, 0, stream>>>(
            XCb, DI, WxB + (size_t)l*145*DI, DI, DTb, DTR, nullptr, 0, BCb, 145, DI);
        scan_a<<<(BB*CH*DQ)/4, 256, 0, stream>>>(UGt, DTb, BCb, Wdt + (size_t)l*DI*DTR, bdt + l*DI,
                                                 A_log + (size_t)l*DI*DS, Q, Sbuf, DELtb);
        scan_c<<<(BB*CH*(DI/2))/4, 256, 0, stream>>>(UGt, DELtb, BCb,
                                                     A_log + (size_t)l*DI*DS, Dd + l*DI, Q, Sbuf, Yb);
        gmfma<0,true><<<dim3(MTOK/128, 3), 256, 0, stream>>>(
            Yb, DI, WoB + (size_t)l*DM*DI, DI, Xb, DM, Xb, DM, nullptr, DM, DI);
    }
    head1_kernel<<<BB*64, 256, 0, stream>>>(Xb, Pt);
    head2_kernel<<<BB, 256, 0, stream>>>(Pt, regw, regb, out);
}

// Round 19
// 1400.183 us; speedup vs baseline: 1.2686x; 1.2686x over previous
//
#include <hip/hip_runtime.h>
#include <hip/hip_bf16.h>
#include <math.h>

#define NL 6
#define DM 272
#define DS 64
#define DI 544
#define DTR 17
#define NSC 4
#define BB 4
#define LL 2048
#define MTOK (BB*LL)
#define TCH 128
#define CH  16
#define DQ  (DI/4)   // 136

typedef __attribute__((ext_vector_type(8))) short bf16x8;
typedef __attribute__((ext_vector_type(4))) float f32x4;

__device__ __forceinline__ float sigmoidf_(float x){ return 1.0f/(1.0f+__expf(-x)); }
__device__ __forceinline__ unsigned short f2bfu(float x){
    union { __hip_bfloat16 h; unsigned short u; } c; c.h = __float2bfloat16(x); return c.u;
}
__device__ __forceinline__ float bfu2f(unsigned short u){ return __uint_as_float(((unsigned)u)<<16); }
__device__ __forceinline__ float bclo(unsigned int bc){ return __uint_as_float(bc << 16); }
__device__ __forceinline__ float bchi(unsigned int bc){ return __uint_as_float(bc & 0xffff0000u); }
__device__ __forceinline__ float exp2x(float x){ float r; asm("v_exp_f32 %0, %1" : "=v"(r) : "v"(x)); return r; }
__device__ __forceinline__ float log2x(float x){ float r; asm("v_log_f32 %0, %1" : "=v"(r) : "v"(x)); return r; }
__device__ __forceinline__ float softplus_(float s){
    float sp = 0.6931471806f * log2x(1.0f + exp2x(s * 1.44269504f));
    return (s > 20.f) ? s : sp;
}

#define DPPADD(x, ctrl) x += __int_as_float(__builtin_amdgcn_update_dpp(0, __float_as_int(x), ctrl, 0xf, 0xf, true))
__device__ __forceinline__ float wsum64(float x){
    DPPADD(x, 0x111); DPPADD(x, 0x112); DPPADD(x, 0x114); DPPADD(x, 0x118);
    DPPADD(x, 0x142); DPPADD(x, 0x143);
    return x;
}

// ---------------- LayerNorm: one wave per token, bf16 output ----------------
__global__ __launch_bounds__(256) void ln_kernel(const float* __restrict__ X,
                          const float* __restrict__ w,
                          const float* __restrict__ b,
                          unsigned short* __restrict__ Hb)
{
    int wave = threadIdx.x >> 6;
    int lane = threadIdx.x & 63;
    int tok = blockIdx.x*4 + wave;
    const float* xr = X + (size_t)tok*DM;
    float v[5];
    float s=0.f, ss=0.f;
    #pragma unroll
    for (int j=0;j<5;++j){
        int idx = lane + j*64;
        float x = (idx < DM) ? xr[idx] : 0.f;
        v[j]=x; s+=x; ss+=x*x;
    }
    #pragma unroll
    for (int off=1; off<64; off<<=1){ s += __shfl_xor(s,off); ss += __shfl_xor(ss,off); }
    float mu  = s * (1.0f/DM);
    float var = ss*(1.0f/DM) - mu*mu;
    float inv = 1.0f/sqrtf(var + 1e-5f);
    unsigned short* hr = Hb + (size_t)tok*DM;
    #pragma unroll
    for (int j=0;j<5;++j){
        int idx = lane + j*64;
        if (idx<DM) hr[idx] = f2bfu((v[j]-mu)*inv*w[idx] + b[idx]);
    }
}

// ======= bf16 MFMA GEMM. OMODE: 0=f32 out, 1=bf16 out, 2=x_proj split (DTb f32 + BCb bf16-pair) =======
template<int OMODE, bool RESID>
__global__ __launch_bounds__(256) void gmfma(const unsigned short* __restrict__ A, int lda,
                     const unsigned short* __restrict__ W, int ldw,
                     void* __restrict__ Cv, int ldc,
                     const float* __restrict__ R, int ldr,
                     void* __restrict__ aux,
                     int N, int K)
{
    __shared__ unsigned short As[128*40];
    __shared__ unsigned short Bs[128*40];
    int bm = blockIdx.x*128, bn = blockIdx.y*128;
    int tid = threadIdx.x;
    int lane = tid & 63, wave = tid >> 6;
    int wm = wave >> 1, wn = wave & 1;
    f32x4 acc[4][4] = {};
    int r16 = lane & 15, kg = (lane >> 4) * 8;
    for (int k0=0; k0<K; k0+=32){
        #pragma unroll
        for (int it=0; it<2; ++it){
            int cid = tid + it*256;
            int row = cid >> 2, kq = (cid & 3)*8;
            int kk = k0 + kq;
            uint4 za = make_uint4(0,0,0,0);
            if (kk < K) za = *(const uint4*)(A + (size_t)(bm+row)*lda + kk);
            *(uint4*)&As[row*40 + kq] = za;
            uint4 zb = make_uint4(0,0,0,0);
            int wr = bn + row;
            if (wr < N && kk < K) zb = *(const uint4*)(W + (size_t)wr*ldw + kk);
            *(uint4*)&Bs[row*40 + kq] = zb;
        }
        __syncthreads();
        bf16x8 af[4], bfr[4];
        #pragma unroll
        for (int mi=0; mi<4; ++mi)
            af[mi] = *(bf16x8*)&As[(wm*64 + mi*16 + r16)*40 + kg];
        #pragma unroll
        for (int ni=0; ni<4; ++ni)
            bfr[ni] = *(bf16x8*)&Bs[(wn*64 + ni*16 + r16)*40 + kg];
        #pragma unroll
        for (int mi=0; mi<4; ++mi)
            #pragma unroll
            for (int ni=0; ni<4; ++ni)
                acc[mi][ni] = __builtin_amdgcn_mfma_f32_16x16x32_bf16(af[mi], bfr[ni], acc[mi][ni], 0, 0, 0);
        __syncthreads();
    }
    int rowt = (lane >> 4)*4, colt = lane & 15;
    #pragma unroll
    for (int mi=0; mi<4; ++mi){
        #pragma unroll
        for (int ni=0; ni<4; ++ni){
            int col = bn + wn*64 + ni*16 + colt;
            if (col < N){
                #pragma unroll
                for (int j=0; j<4; ++j){
                    int row = bm + wm*64 + mi*16 + rowt + j;
                    float v = acc[mi][ni][j];
                    if (RESID) v += R[(size_t)row*ldr + col];
                    if (OMODE == 0)
                        ((float*)Cv)[(size_t)row*ldc + col] = v;
                    else if (OMODE == 1)
                        ((unsigned short*)Cv)[(size_t)row*ldc + col] = f2bfu(v);
                    else {
                        if (col < DTR)
                            ((float*)Cv)[(size_t)row*DTR + col] = v;
                        else if (col < DTR + DS)
                            ((unsigned short*)aux)[((size_t)row*DS + col - DTR)*2] = f2bfu(v);
                        else
                            ((unsigned short*)aux)[((size_t)row*DS + col - DTR - DS)*2 + 1] = f2bfu(v);
                    }
                }
            }
        }
    }
}

// ------- conv+SiLU+gate (bf16 in): outputs UGt uint32 {lo:u, hi:g} [d][t] + XCb bf16 [tok][d] -------
__global__ __launch_bounds__(256) void conv_t2_kernel(const unsigned short* __restrict__ XZb,
                                 const float* __restrict__ cw,
                                 const float* __restrict__ cb,
                                 unsigned int* __restrict__ UGt,
                                 unsigned short* __restrict__ XCb)
{
    __shared__ float xi[67][69];
    __shared__ float zz[64][69];
    int bid = blockIdx.x;
    int b  = bid >> 8;
    int rem = bid & 255;
    int t0 = (rem >> 3)*64;
    int d0 = (rem & 7)*68;
    int tid = threadIdx.x;
    for (int li = tid; li < 67*17; li += 256){
        int row = li / 17, q = li - row*17;
        int tg = t0 - 3 + row;
        float4 v = make_float4(0.f,0.f,0.f,0.f);
        if (tg >= 0){
            ushort4 u4 = *(const ushort4*)(XZb + ((size_t)b*LL + tg)*(2*DI) + d0 + q*4);
            v.x = bfu2f(u4.x); v.y = bfu2f(u4.y); v.z = bfu2f(u4.z); v.w = bfu2f(u4.w);
        }
        xi[row][q*4+0]=v.x; xi[row][q*4+1]=v.y; xi[row][q*4+2]=v.z; xi[row][q*4+3]=v.w;
    }
    for (int li = tid; li < 64*17; li += 256){
        int row = li / 17, q = li - row*17;
        ushort4 u4 = *(const ushort4*)(XZb + ((size_t)b*LL + t0 + row)*(2*DI) + DI + d0 + q*4);
        zz[row][q*4+0]=bfu2f(u4.x); zz[row][q*4+1]=bfu2f(u4.y);
        zz[row][q*4+2]=bfu2f(u4.z); zz[row][q*4+3]=bfu2f(u4.w);
    }
    __syncthreads();
    int t = tid & 63;
    int dw = tid >> 6;
    float xcreg[17];
    #pragma unroll
    for (int i=0; i<17; ++i){
        int dl = dw + i*4;
        int d = d0 + dl;
        const float* cwd = cw + d*4;
        float acc = cb[d];
        #pragma unroll
        for (int k=0;k<4;++k) acc = fmaf(xi[t+k][dl], cwd[k], acc);
        float xc = acc * sigmoidf_(acc);
        float z  = zz[t][dl];
        size_t o = ((size_t)b*DI + d)*LL + t0 + t;
        float g = z * sigmoidf_(z);
        UGt[o] = (unsigned int)f2bfu(xc) | ((unsigned int)f2bfu(g) << 16);
        xcreg[i] = xc;
    }
    __syncthreads();
    #pragma unroll
    for (int i=0; i<17; ++i) zz[t][dw + i*4] = xcreg[i];
    __syncthreads();
    for (int li = tid; li < 64*17; li += 256){
        int row = li / 17, q = li - row*17;
        ushort4 v;
        v.x = f2bfu(zz[row][q*4+0]); v.y = f2bfu(zz[row][q*4+1]);
        v.z = f2bfu(zz[row][q*4+2]); v.w = f2bfu(zz[row][q*4+3]);
        *(ushort4*)&XCb[((size_t)b*LL + t0 + row)*DI + d0 + q*4] = v;
    }
}

// ======= chunked scan, pass A: 4 ch/wave, fused dt (contiguous DTb), BCb dword loads =======
__global__ __launch_bounds__(256) void scan_a(const unsigned int* __restrict__ UGt,
                       const float* __restrict__ DTb,
                       const unsigned int* __restrict__ BCb,
                       const float* __restrict__ Wdt,
                       const float* __restrict__ bdt,
                       const float* __restrict__ A_log,
                       float* __restrict__ Q,
                       float* __restrict__ S,
                       unsigned short* __restrict__ DELtb)
{
    __shared__ __align__(16) float2 dlb[4][4][64];
    int tid = threadIdx.x;
    int wave = tid >> 6, lane = tid & 63;
    float2 (*Db)[64] = dlb[wave];
    int wid = blockIdx.x*4 + wave;            // (b, c, dd) dd fastest
    int dd = wid % DQ;
    int c  = (wid / DQ) % CH;
    int b  = wid / (DQ*CH);
    int d0 = dd, d1 = dd+DQ, d2 = dd+2*DQ, d3 = dd+3*DQ;
    const float L2E = 1.44269504f;
    float Av0 = -__expf(A_log[d0*DS + lane]) * L2E;
    float Av1 = -__expf(A_log[d1*DS + lane]) * L2E;
    float Av2 = -__expf(A_log[d2*DS + lane]) * L2E;
    float Av3 = -__expf(A_log[d3*DS + lane]) * L2E;
    const float* wd0 = Wdt + d0*DTR;
    const float* wd1 = Wdt + d1*DTR;
    const float* wd2 = Wdt + d2*DTR;
    const float* wd3 = Wdt + d3*DTR;
    float h0=0.f,h1=0.f,h2=0.f,h3=0.f, ds0=0.f,ds1=0.f,ds2=0.f,ds3=0.f;
    size_t tokBase = (size_t)b*LL + (size_t)c*TCH;
    size_t rb0 = ((size_t)b*DI + d0)*LL + c*TCH;
    size_t rb1 = ((size_t)b*DI + d1)*LL + c*TCH;
    size_t rb2 = ((size_t)b*DI + d2)*LL + c*TCH;
    size_t rb3 = ((size_t)b*DI + d3)*LL + c*TCH;
    for (int blk=0; blk<TCH/64; ++blk){
        // fused dt_proj: contiguous 17-f32 gather per token, streaming accumulation
        const float* dp = DTb + (tokBase + blk*64 + lane)*DTR;
        float s0=bdt[d0], s1=bdt[d1], s2=bdt[d2], s3=bdt[d3];
        #pragma unroll
        for (int r=0;r<17;++r){
            float d = dp[r];
            s0 = fmaf(d, wd0[r], s0);
            s1 = fmaf(d, wd1[r], s1);
            s2 = fmaf(d, wd2[r], s2);
            s3 = fmaf(d, wd3[r], s3);
        }
        float dl0 = softplus_(s0), dl1 = softplus_(s1);
        float dl2 = softplus_(s2), dl3 = softplus_(s3);
        size_t o0 = rb0 + blk*64 + lane, o1 = rb1 + blk*64 + lane;
        size_t o2 = rb2 + blk*64 + lane, o3 = rb3 + blk*64 + lane;
        DELtb[o0] = f2bfu(dl0); DELtb[o1] = f2bfu(dl1);
        DELtb[o2] = f2bfu(dl2); DELtb[o3] = f2bfu(dl3);
        float du0 = dl0*bfu2f((unsigned short)UGt[o0]);
        float du1 = dl1*bfu2f((unsigned short)UGt[o1]);
        float du2 = dl2*bfu2f((unsigned short)UGt[o2]);
        float du3 = dl3*bfu2f((unsigned short)UGt[o3]);
        ds0 += dl0; ds1 += dl1; ds2 += dl2; ds3 += dl3;
        Db[0][lane] = make_float2(dl0, du0);
        Db[1][lane] = make_float2(dl1, du1);
        Db[2][lane] = make_float2(dl2, du2);
        Db[3][lane] = make_float2(dl3, du3);
        const unsigned int* pbc = BCb + (tokBase + blk*64)*DS;
        #pragma unroll 1
        for (int g=0; g<8; ++g){
            const float2* q0 = &Db[0][g*8];
            const float2* q1 = &Db[1][g*8];
            const float2* q2 = &Db[2][g*8];
            const float2* q3 = &Db[3][g*8];
            #pragma unroll
            for (int i=0; i<8; ++i){
                float Bv = bclo(pbc[lane]);
                float2 a0=q0[i], a1=q1[i], a2=q2[i], a3=q3[i];
                h0 = fmaf(exp2x(a0.x*Av0), h0, a0.y*Bv);
                h1 = fmaf(exp2x(a1.x*Av1), h1, a1.y*Bv);
                h2 = fmaf(exp2x(a2.x*Av2), h2, a2.y*Bv);
                h3 = fmaf(exp2x(a3.x*Av3), h3, a3.y*Bv);
                pbc += DS;
            }
        }
    }
    size_t q0i = ((size_t)b*DI + d0)*CH + c, q1i = ((size_t)b*DI + d1)*CH + c;
    size_t q2i = ((size_t)b*DI + d2)*CH + c, q3i = ((size_t)b*DI + d3)*CH + c;
    Q[q0i*64 + lane] = h0; Q[q1i*64 + lane] = h1;
    Q[q2i*64 + lane] = h2; Q[q3i*64 + lane] = h3;
    float s0w = wsum64(ds0), s1w = wsum64(ds1), s2w = wsum64(ds2), s3w = wsum64(ds3);
    if (lane == 63){ S[q0i]=s0w; S[q1i]=s1w; S[q2i]=s2w; S[q3i]=s3w; }
}

// ======= chunked scan, pass C: 2 ch/wave, packed BC, XCD-swizzled blocks, Yst-staged out =======
__global__ __launch_bounds__(256) void scan_c(const unsigned int* __restrict__ UGt,
                       const unsigned short* __restrict__ DELtb,
                       const unsigned int* __restrict__ BCb,
                       const float* __restrict__ A_log,
                       const float* __restrict__ Dskip,
                       const float* __restrict__ Q,
                       const float* __restrict__ S,
                       unsigned short* __restrict__ Yb)
{
    __shared__ float P[4][2][4][76];
    __shared__ float Ypark[4][2][4];
    __shared__ __align__(16) float2 dlb[4][2][64];
    __shared__ unsigned short Yst[64][12];
    int tid = threadIdx.x;
    int wave = tid >> 6, lane = tid & 63;
    float (*Pr0)[76] = P[wave][0];
    float (*Pr1)[76] = P[wave][1];
    float* Yp0 = Ypark[wave][0];
    float* Yp1 = Ypark[wave][1];
    float2* Db0 = dlb[wave][0];
    float2* Db1 = dlb[wave][1];
    // XCD-bijective swizzle: grid = 4352 = 8*544. Consecutive logical blocks (adjacent dd,
    // same (b,c) row-range) land on the SAME XCD so its L2 assembles full 64B lines from
    // the 8B Yb pieces (kills partial-line writebacks).
    int sb = (blockIdx.x & 7)*544 + (blockIdx.x >> 3);
    int wid = sb*4 + wave;                    // 4 waves share (b,c); dd consecutive
    int dd = wid % (DI/2);
    int c  = (wid / (DI/2)) % CH;
    int b  = wid / ((DI/2)*CH);
    int d0 = dd, d1 = dd + DI/2;
    int wid0 = sb*4;
    int dd0b = wid0 % (DI/2);
    int cB = (wid0 / (DI/2)) % CH;
    int bB = wid0 / ((DI/2)*CH);
    const float L2E = 1.44269504f;
    float Av0 = -__expf(A_log[d0*DS + lane]) * L2E;
    float Av1 = -__expf(A_log[d1*DS + lane]) * L2E;
    float Dd0 = Dskip[d0], Dd1 = Dskip[d1];
    size_t q0 = ((size_t)b*DI + d0)*CH, q1 = ((size_t)b*DI + d1)*CH;
    float h0=0.f, h1=0.f;
    for (int j=0; j<c; ++j){
        h0 = fmaf(exp2x(Av0*S[q0+j]), h0, Q[(q0+j)*64 + lane]);
        h1 = fmaf(exp2x(Av1*S[q1+j]), h1, Q[(q1+j)*64 + lane]);
    }
    size_t tokBase = (size_t)b*LL + (size_t)c*TCH;
    size_t rb0 = ((size_t)b*DI + d0)*LL + c*TCH;
    size_t rb1 = ((size_t)b*DI + d1)*LL + c*TCH;
    int fr = lane >> 4, fq = (lane & 15)*4;
    for (int blk=0; blk<TCH/64; ++blk){
        size_t o0 = rb0 + blk*64 + lane, o1 = rb1 + blk*64 + lane;
        float dl0 = bfu2f(DELtb[o0]), dl1 = bfu2f(DELtb[o1]);
        unsigned int ug0 = UGt[o0], ug1 = UGt[o1];
        float ul0 = bfu2f((unsigned short)ug0), ul1 = bfu2f((unsigned short)ug1);
        float gl0 = bfu2f((unsigned short)(ug0 >> 16)), gl1 = bfu2f((unsigned short)(ug1 >> 16));
        Db0[lane] = make_float2(dl0, dl0*ul0);
        Db1[lane] = make_float2(dl1, dl1*ul1);
        float y0=0.f, y1=0.f;
        const unsigned int* pbc = BCb + (tokBase + blk*64)*DS;
        #pragma unroll 1
        for (int f=0; f<16; ++f){
            float4 pa0 = *(const float4*)&Db0[f*4];     // steps 0,1: (dl,du,dl,du)
            float4 pa1 = *(const float4*)&Db0[f*4+2];   // steps 2,3
            float4 pb0 = *(const float4*)&Db1[f*4];
            float4 pb1 = *(const float4*)&Db1[f*4+2];
            #pragma unroll
            for (int i=0; i<4; ++i){
                unsigned int bc = pbc[lane];
                float Bv = bclo(bc);
                float Cv = bchi(bc);
                float d0v = (i==0)?pa0.x:(i==1)?pa0.z:(i==2)?pa1.x:pa1.z;
                float u0v = (i==0)?pa0.y:(i==1)?pa0.w:(i==2)?pa1.y:pa1.w;
                float d1v = (i==0)?pb0.x:(i==1)?pb0.z:(i==2)?pb1.x:pb1.z;
                float u1v = (i==0)?pb0.y:(i==1)?pb0.w:(i==2)?pb1.y:pb1.w;
                h0 = fmaf(exp2x(d0v*Av0), h0, u0v*Bv);
                h1 = fmaf(exp2x(d1v*Av1), h1, u1v*Bv);
                Pr0[i][lane] = h0*Cv;
                Pr1[i][lane] = h1*Cv;
                pbc += DS;
            }
            float4 xa0 = *(const float4*)&Pr0[fr][fq];
            float s0f = (xa0.x+xa0.y)+(xa0.z+xa0.w);
            DPPADD(s0f,0x111); DPPADD(s0f,0x112); DPPADD(s0f,0x114); DPPADD(s0f,0x118);
            float4 xa1 = *(const float4*)&Pr1[fr][fq];
            float s1f = (xa1.x+xa1.y)+(xa1.z+xa1.w);
            DPPADD(s1f,0x111); DPPADD(s1f,0x112); DPPADD(s1f,0x114); DPPADD(s1f,0x118);
            if ((lane & 15) == 15){ Yp0[fr] = s0f; Yp1[fr] = s1f; }
            float g0 = Yp0[lane & 3];
            float g1 = Yp1[lane & 3];
            if ((lane >> 2) == f){ y0 = g0; y1 = g1; }
        }
        Yst[lane][wave]     = f2bfu((y0 + ul0*Dd0)*gl0);
        Yst[lane][4 + wave] = f2bfu((y1 + ul1*Dd1)*gl1);
        __syncthreads();
        if (tid < 128){
            int row = tid & 63, grp = tid >> 6;
            ushort4 v = *(const ushort4*)&Yst[row][grp*4];
            size_t trow = (size_t)bB*LL + (size_t)cB*TCH + blk*64 + row;
            *(ushort4*)&Yb[trow*DI + dd0b + grp*(DI/2)] = v;
        }
        __syncthreads();
    }
}

// ------- weight f32 -> bf16 convert -------
__global__ __launch_bounds__(256) void wconv_kernel(const float* __restrict__ src,
                            unsigned short* __restrict__ dst,
                            int total, int kin, int kout)
{
    int idx = blockIdx.x*256 + threadIdx.x;
    if (idx >= total) return;
    int r = idx / kout, c = idx - r*kout;
    float v = (c < kin) ? src[(size_t)r*kin + c] : 0.f;
    dst[idx] = f2bfu(v);
}

// ------- head: two-stage mean-pool + regression -------
__global__ __launch_bounds__(256) void head1_kernel(const float* __restrict__ X,
                             float* __restrict__ Pt)
{
    int b = blockIdx.x >> 6, c = blockIdx.x & 63;
    int tid = threadIdx.x;
    for (int dm = tid; dm < DM; dm += 256){
        float s = 0.f;
        const float* base = X + ((size_t)b*LL + c*32)*DM + dm;
        #pragma unroll 8
        for (int tt=0; tt<32; ++tt) s += base[(size_t)tt*DM];
        Pt[(size_t)(b*64 + c)*DM + dm] = s;
    }
}

__global__ __launch_bounds__(256) void head2_kernel(const float* __restrict__ Pt,
                             const float* __restrict__ reg_w,
                             const float* __restrict__ reg_b,
                             float* __restrict__ out)
{
    __shared__ float feat[DM];
    int b = blockIdx.x, tid = threadIdx.x;
    for (int dm = tid; dm < DM; dm += 256){
        float s = 0.f;
        for (int c=0; c<64; ++c) s += Pt[(size_t)(b*64 + c)*DM + dm];
        float f = s * (1.0f/LL);
        feat[dm] = f;
        out[16 + b*DM + dm] = f;
    }
    __syncthreads();
    if (tid < NSC){
        float s = reg_b[tid];
        const float* wr = reg_w + tid*DM;
        for (int k=0;k<DM;++k) s = fmaf(feat[k], wr[k], s);
        out[b*NSC + tid] = s;
    }
}

extern "C" void kernel_launch(void* const* d_in, const int* in_sizes, int n_in,
                              void* d_out, int out_size, void* d_ws, size_t ws_size,
                              hipStream_t stream)
{
    const float* x_in  = (const float*)d_in[0];
    const float* ln_w  = (const float*)d_in[1];
    const float* ln_b  = (const float*)d_in[2];
    const float* Wi    = (const float*)d_in[3];
    const float* cw    = (const float*)d_in[4];
    const float* cb    = (const float*)d_in[5];
    const float* Wx    = (const float*)d_in[6];
    const float* Wdt   = (const float*)d_in[7];
    const float* bdt   = (const float*)d_in[8];
    const float* A_log = (const float*)d_in[9];
    const float* Dd    = (const float*)d_in[10];
    const float* Wo    = (const float*)d_in[11];
    const float* regw  = (const float*)d_in[12];
    const float* regb  = (const float*)d_in[13];
    float* out = (float*)d_out;

    char* base = (char*)d_ws;
    auto carve = [&](size_t bytes) -> char* {
        char* p = base; base += (bytes + 255) & ~(size_t)255; return p;
    };
    unsigned short* XZb   = (unsigned short*)carve((size_t)MTOK*1088*2);
    unsigned int*   UGt   = (unsigned int*)carve((size_t)MTOK*544*4);
    unsigned short* DELtb = (unsigned short*)carve((size_t)MTOK*544*2);
    float*          DTb   = (float*)carve((size_t)MTOK*DTR*4);
    unsigned int*   BCb   = (unsigned int*)carve((size_t)MTOK*DS*4);
    float*          Xb    = (float*)carve((size_t)MTOK*272*4);
    unsigned short* Yb    = (unsigned short*)carve((size_t)MTOK*544*2);
    char*           SCR   = carve((size_t)MTOK*272*4);   // Hb / XCb / Q / Pt overlay
    float*          Sbuf  = (float*)carve((size_t)BB*DI*CH*4);
    unsigned short* WiB   = (unsigned short*)carve((size_t)NL*1088*DM*2);
    unsigned short* WxB   = (unsigned short*)carve((size_t)NL*145*DI*2);
    unsigned short* WoB   = (unsigned short*)carve((size_t)NL*272*DI*2);

    unsigned short* Hb  = (unsigned short*)SCR;
    unsigned short* XCb = (unsigned short*)SCR;
    float*          Q   = (float*)SCR;
    float*          Pt  = (float*)SCR;

    (void)hipMemcpyAsync(Xb, x_in, sizeof(float)*(size_t)MTOK*DM, hipMemcpyDeviceToDevice, stream);

    wconv_kernel<<<(NL*1088*DM + 255)/256, 256, 0, stream>>>(Wi, WiB, NL*1088*DM, DM, DM);
    wconv_kernel<<<(NL*145*DI + 255)/256, 256, 0, stream>>>(Wx, WxB, NL*145*DI, DI, DI);
    wconv_kernel<<<(NL*272*DI + 255)/256, 256, 0, stream>>>(Wo, WoB, NL*272*DI, DI, DI);

    for (int l=0; l<NL; ++l){
        ln_kernel<<<MTOK/4, 256, 0, stream>>>(Xb, ln_w + l*DM, ln_b + l*DM, Hb);
        gmfma<1,false><<<dim3(MTOK/128, (2*DI+127)/128), 256, 0, stream>>>(
            Hb, DM, WiB + (size_t)l*2*DI*DM, DM, XZb, 2*DI, nullptr, 0, nullptr, 2*DI, DM);
        conv_t2_kernel<<<BB*256, 256, 0, stream>>>(XZb, cw + l*DI*4, cb + l*DI, UGt, XCb);
        gmfma<2,false><<<dim3(MTOK/128, 2), 256, 0, stream>>>(
            XCb, DI, WxB + (size_t)l*145*DI, DI, DTb, DTR, nullptr, 0, BCb, 145, DI);
        scan_a<<<(BB*CH*DQ)/4, 256, 0, stream>>>(UGt, DTb, BCb, Wdt + (size_t)l*DI*DTR, bdt + l*DI,
                                                 A_log + (size_t)l*DI*DS, Q, Sbuf, DELtb);
        scan_c<<<(BB*CH*(DI/2))/4, 256, 0, stream>>>(UGt, DELtb, BCb,
                                                     A_log + (size_t)l*DI*DS, Dd + l*DI, Q, Sbuf, Yb);
        gmfma<0,true><<<dim3(MTOK/128, 3), 256, 0, stream>>>(
            Yb, DI, WoB + (size_t)l*DM*DI, DI, Xb, DM, Xb, DM, nullptr, DM, DI);
    }
    head1_kernel<<<BB*64, 256, 0, stream>>>(Xb, Pt);
    head2_kernel<<<BB, 256, 0, stream>>>(Pt, regw, regb, out);
}

// Round 20
// 1396.976 us; speedup vs baseline: 1.2716x; 1.0023x over previous
//
#include <hip/hip_runtime.h>
#include <hip/hip_bf16.h>
#include <math.h>

#define NL 6
#define DM 272
#define DS 64
#define DI 544
#define DTR 17
#define NSC 4
#define BB 4
#define LL 2048
#define MTOK (BB*LL)
#define TCH 128
#define CH  16
#define DQ  (DI/4)   // 136

typedef __attribute__((ext_vector_type(8))) short bf16x8;
typedef __attribute__((ext_vector_type(4))) float f32x4;
typedef __attribute__((ext_vector_type(2))) float f32x2;

__device__ __forceinline__ float sigmoidf_(float x){ return 1.0f/(1.0f+__expf(-x)); }
__device__ __forceinline__ unsigned short f2bfu(float x){
    union { __hip_bfloat16 h; unsigned short u; } c; c.h = __float2bfloat16(x); return c.u;
}
__device__ __forceinline__ float bfu2f(unsigned short u){ return __uint_as_float(((unsigned)u)<<16); }
__device__ __forceinline__ float bclo(unsigned int bc){ return __uint_as_float(bc << 16); }
__device__ __forceinline__ float bchi(unsigned int bc){ return __uint_as_float(bc & 0xffff0000u); }
__device__ __forceinline__ float exp2x(float x){ float r; asm("v_exp_f32 %0, %1" : "=v"(r) : "v"(x)); return r; }
__device__ __forceinline__ float log2x(float x){ float r; asm("v_log_f32 %0, %1" : "=v"(r) : "v"(x)); return r; }
__device__ __forceinline__ float softplus_(float s){
    float sp = 0.6931471806f * log2x(1.0f + exp2x(s * 1.44269504f));
    return (s > 20.f) ? s : sp;
}
// CDNA packed f32 (VOP3P): 2 f32 ops in one instruction on VGPR pairs
__device__ __forceinline__ f32x2 pk_mul2(f32x2 a, f32x2 b){
    f32x2 d; asm("v_pk_mul_f32 %0, %1, %2" : "=v"(d) : "v"(a), "v"(b)); return d;
}
__device__ __forceinline__ f32x2 pk_fma2(f32x2 a, f32x2 b, f32x2 c){
    f32x2 d; asm("v_pk_fma_f32 %0, %1, %2, %3" : "=v"(d) : "v"(a), "v"(b), "v"(c)); return d;
}

#define DPPADD(x, ctrl) x += __int_as_float(__builtin_amdgcn_update_dpp(0, __float_as_int(x), ctrl, 0xf, 0xf, true))
__device__ __forceinline__ float wsum64(float x){
    DPPADD(x, 0x111); DPPADD(x, 0x112); DPPADD(x, 0x114); DPPADD(x, 0x118);
    DPPADD(x, 0x142); DPPADD(x, 0x143);
    return x;
}

// ---------------- LayerNorm: one wave per token, bf16 output ----------------
__global__ __launch_bounds__(256) void ln_kernel(const float* __restrict__ X,
                          const float* __restrict__ w,
                          const float* __restrict__ b,
                          unsigned short* __restrict__ Hb)
{
    int wave = threadIdx.x >> 6;
    int lane = threadIdx.x & 63;
    int tok = blockIdx.x*4 + wave;
    const float* xr = X + (size_t)tok*DM;
    float v[5];
    float s=0.f, ss=0.f;
    #pragma unroll
    for (int j=0;j<5;++j){
        int idx = lane + j*64;
        float x = (idx < DM) ? xr[idx] : 0.f;
        v[j]=x; s+=x; ss+=x*x;
    }
    #pragma unroll
    for (int off=1; off<64; off<<=1){ s += __shfl_xor(s,off); ss += __shfl_xor(ss,off); }
    float mu  = s * (1.0f/DM);
    float var = ss*(1.0f/DM) - mu*mu;
    float inv = 1.0f/sqrtf(var + 1e-5f);
    unsigned short* hr = Hb + (size_t)tok*DM;
    #pragma unroll
    for (int j=0;j<5;++j){
        int idx = lane + j*64;
        if (idx<DM) hr[idx] = f2bfu((v[j]-mu)*inv*w[idx] + b[idx]);
    }
}

// ======= bf16 MFMA GEMM. OMODE: 0=f32 out, 1=bf16 out, 2=x_proj split (DTb f32 + BCb bf16-pair) =======
template<int OMODE, bool RESID>
__global__ __launch_bounds__(256) void gmfma(const unsigned short* __restrict__ A, int lda,
                     const unsigned short* __restrict__ W, int ldw,
                     void* __restrict__ Cv, int ldc,
                     const float* __restrict__ R, int ldr,
                     void* __restrict__ aux,
                     int N, int K)
{
    __shared__ unsigned short As[128*40];
    __shared__ unsigned short Bs[128*40];
    int bm = blockIdx.x*128, bn = blockIdx.y*128;
    int tid = threadIdx.x;
    int lane = tid & 63, wave = tid >> 6;
    int wm = wave >> 1, wn = wave & 1;
    f32x4 acc[4][4] = {};
    int r16 = lane & 15, kg = (lane >> 4) * 8;
    for (int k0=0; k0<K; k0+=32){
        #pragma unroll
        for (int it=0; it<2; ++it){
            int cid = tid + it*256;
            int row = cid >> 2, kq = (cid & 3)*8;
            int kk = k0 + kq;
            uint4 za = make_uint4(0,0,0,0);
            if (kk < K) za = *(const uint4*)(A + (size_t)(bm+row)*lda + kk);
            *(uint4*)&As[row*40 + kq] = za;
            uint4 zb = make_uint4(0,0,0,0);
            int wr = bn + row;
            if (wr < N && kk < K) zb = *(const uint4*)(W + (size_t)wr*ldw + kk);
            *(uint4*)&Bs[row*40 + kq] = zb;
        }
        __syncthreads();
        bf16x8 af[4], bfr[4];
        #pragma unroll
        for (int mi=0; mi<4; ++mi)
            af[mi] = *(bf16x8*)&As[(wm*64 + mi*16 + r16)*40 + kg];
        #pragma unroll
        for (int ni=0; ni<4; ++ni)
            bfr[ni] = *(bf16x8*)&Bs[(wn*64 + ni*16 + r16)*40 + kg];
        #pragma unroll
        for (int mi=0; mi<4; ++mi)
            #pragma unroll
            for (int ni=0; ni<4; ++ni)
                acc[mi][ni] = __builtin_amdgcn_mfma_f32_16x16x32_bf16(af[mi], bfr[ni], acc[mi][ni], 0, 0, 0);
        __syncthreads();
    }
    int rowt = (lane >> 4)*4, colt = lane & 15;
    #pragma unroll
    for (int mi=0; mi<4; ++mi){
        #pragma unroll
        for (int ni=0; ni<4; ++ni){
            int col = bn + wn*64 + ni*16 + colt;
            if (col < N){
                #pragma unroll
                for (int j=0; j<4; ++j){
                    int row = bm + wm*64 + mi*16 + rowt + j;
                    float v = acc[mi][ni][j];
                    if (RESID) v += R[(size_t)row*ldr + col];
                    if (OMODE == 0)
                        ((float*)Cv)[(size_t)row*ldc + col] = v;
                    else if (OMODE == 1)
                        ((unsigned short*)Cv)[(size_t)row*ldc + col] = f2bfu(v);
                    else {
                        if (col < DTR)
                            ((float*)Cv)[(size_t)row*DTR + col] = v;
                        else if (col < DTR + DS)
                            ((unsigned short*)aux)[((size_t)row*DS + col - DTR)*2] = f2bfu(v);
                        else
                            ((unsigned short*)aux)[((size_t)row*DS + col - DTR - DS)*2 + 1] = f2bfu(v);
                    }
                }
            }
        }
    }
}

// ------- conv+SiLU+gate (bf16 in): outputs UGt uint32 {lo:u, hi:g} [d][t] + XCb bf16 [tok][d] -------
__global__ __launch_bounds__(256) void conv_t2_kernel(const unsigned short* __restrict__ XZb,
                                 const float* __restrict__ cw,
                                 const float* __restrict__ cb,
                                 unsigned int* __restrict__ UGt,
                                 unsigned short* __restrict__ XCb)
{
    __shared__ float xi[67][69];
    __shared__ float zz[64][69];
    int bid = blockIdx.x;
    int b  = bid >> 8;
    int rem = bid & 255;
    int t0 = (rem >> 3)*64;
    int d0 = (rem & 7)*68;
    int tid = threadIdx.x;
    for (int li = tid; li < 67*17; li += 256){
        int row = li / 17, q = li - row*17;
        int tg = t0 - 3 + row;
        float4 v = make_float4(0.f,0.f,0.f,0.f);
        if (tg >= 0){
            ushort4 u4 = *(const ushort4*)(XZb + ((size_t)b*LL + tg)*(2*DI) + d0 + q*4);
            v.x = bfu2f(u4.x); v.y = bfu2f(u4.y); v.z = bfu2f(u4.z); v.w = bfu2f(u4.w);
        }
        xi[row][q*4+0]=v.x; xi[row][q*4+1]=v.y; xi[row][q*4+2]=v.z; xi[row][q*4+3]=v.w;
    }
    for (int li = tid; li < 64*17; li += 256){
        int row = li / 17, q = li - row*17;
        ushort4 u4 = *(const ushort4*)(XZb + ((size_t)b*LL + t0 + row)*(2*DI) + DI + d0 + q*4);
        zz[row][q*4+0]=bfu2f(u4.x); zz[row][q*4+1]=bfu2f(u4.y);
        zz[row][q*4+2]=bfu2f(u4.z); zz[row][q*4+3]=bfu2f(u4.w);
    }
    __syncthreads();
    int t = tid & 63;
    int dw = tid >> 6;
    float xcreg[17];
    #pragma unroll
    for (int i=0; i<17; ++i){
        int dl = dw + i*4;
        int d = d0 + dl;
        const float* cwd = cw + d*4;
        float acc = cb[d];
        #pragma unroll
        for (int k=0;k<4;++k) acc = fmaf(xi[t+k][dl], cwd[k], acc);
        float xc = acc * sigmoidf_(acc);
        float z  = zz[t][dl];
        size_t o = ((size_t)b*DI + d)*LL + t0 + t;
        float g = z * sigmoidf_(z);
        UGt[o] = (unsigned int)f2bfu(xc) | ((unsigned int)f2bfu(g) << 16);
        xcreg[i] = xc;
    }
    __syncthreads();
    #pragma unroll
    for (int i=0; i<17; ++i) zz[t][dw + i*4] = xcreg[i];
    __syncthreads();
    for (int li = tid; li < 64*17; li += 256){
        int row = li / 17, q = li - row*17;
        ushort4 v;
        v.x = f2bfu(zz[row][q*4+0]); v.y = f2bfu(zz[row][q*4+1]);
        v.z = f2bfu(zz[row][q*4+2]); v.w = f2bfu(zz[row][q*4+3]);
        *(ushort4*)&XCb[((size_t)b*LL + t0 + row)*DI + d0 + q*4] = v;
    }
}

// ======= chunked scan, pass A: 4 ch/wave, fused dt (contiguous DTb), BCb dword loads =======
__global__ __launch_bounds__(256) void scan_a(const unsigned int* __restrict__ UGt,
                       const float* __restrict__ DTb,
                       const unsigned int* __restrict__ BCb,
                       const float* __restrict__ Wdt,
                       const float* __restrict__ bdt,
                       const float* __restrict__ A_log,
                       float* __restrict__ Q,
                       float* __restrict__ S,
                       unsigned short* __restrict__ DELtb)
{
    __shared__ __align__(16) float2 dlb[4][4][64];
    int tid = threadIdx.x;
    int wave = tid >> 6, lane = tid & 63;
    float2 (*Db)[64] = dlb[wave];
    int wid = blockIdx.x*4 + wave;            // (b, c, dd) dd fastest
    int dd = wid % DQ;
    int c  = (wid / DQ) % CH;
    int b  = wid / (DQ*CH);
    int d0 = dd, d1 = dd+DQ, d2 = dd+2*DQ, d3 = dd+3*DQ;
    const float L2E = 1.44269504f;
    float Av0 = -__expf(A_log[d0*DS + lane]) * L2E;
    float Av1 = -__expf(A_log[d1*DS + lane]) * L2E;
    float Av2 = -__expf(A_log[d2*DS + lane]) * L2E;
    float Av3 = -__expf(A_log[d3*DS + lane]) * L2E;
    const float* wd0 = Wdt + d0*DTR;
    const float* wd1 = Wdt + d1*DTR;
    const float* wd2 = Wdt + d2*DTR;
    const float* wd3 = Wdt + d3*DTR;
    float h0=0.f,h1=0.f,h2=0.f,h3=0.f, ds0=0.f,ds1=0.f,ds2=0.f,ds3=0.f;
    size_t tokBase = (size_t)b*LL + (size_t)c*TCH;
    size_t rb0 = ((size_t)b*DI + d0)*LL + c*TCH;
    size_t rb1 = ((size_t)b*DI + d1)*LL + c*TCH;
    size_t rb2 = ((size_t)b*DI + d2)*LL + c*TCH;
    size_t rb3 = ((size_t)b*DI + d3)*LL + c*TCH;
    for (int blk=0; blk<TCH/64; ++blk){
        const float* dp = DTb + (tokBase + blk*64 + lane)*DTR;
        float s0=bdt[d0], s1=bdt[d1], s2=bdt[d2], s3=bdt[d3];
        #pragma unroll
        for (int r=0;r<17;++r){
            float d = dp[r];
            s0 = fmaf(d, wd0[r], s0);
            s1 = fmaf(d, wd1[r], s1);
            s2 = fmaf(d, wd2[r], s2);
            s3 = fmaf(d, wd3[r], s3);
        }
        float dl0 = softplus_(s0), dl1 = softplus_(s1);
        float dl2 = softplus_(s2), dl3 = softplus_(s3);
        size_t o0 = rb0 + blk*64 + lane, o1 = rb1 + blk*64 + lane;
        size_t o2 = rb2 + blk*64 + lane, o3 = rb3 + blk*64 + lane;
        DELtb[o0] = f2bfu(dl0); DELtb[o1] = f2bfu(dl1);
        DELtb[o2] = f2bfu(dl2); DELtb[o3] = f2bfu(dl3);
        float du0 = dl0*bfu2f((unsigned short)UGt[o0]);
        float du1 = dl1*bfu2f((unsigned short)UGt[o1]);
        float du2 = dl2*bfu2f((unsigned short)UGt[o2]);
        float du3 = dl3*bfu2f((unsigned short)UGt[o3]);
        ds0 += dl0; ds1 += dl1; ds2 += dl2; ds3 += dl3;
        Db[0][lane] = make_float2(dl0, du0);
        Db[1][lane] = make_float2(dl1, du1);
        Db[2][lane] = make_float2(dl2, du2);
        Db[3][lane] = make_float2(dl3, du3);
        const unsigned int* pbc = BCb + (tokBase + blk*64)*DS;
        #pragma unroll 1
        for (int g=0; g<8; ++g){
            const float2* q0 = &Db[0][g*8];
            const float2* q1 = &Db[1][g*8];
            const float2* q2 = &Db[2][g*8];
            const float2* q3 = &Db[3][g*8];
            #pragma unroll
            for (int i=0; i<8; ++i){
                float Bv = bclo(pbc[lane]);
                float2 a0=q0[i], a1=q1[i], a2=q2[i], a3=q3[i];
                h0 = fmaf(exp2x(a0.x*Av0), h0, a0.y*Bv);
                h1 = fmaf(exp2x(a1.x*Av1), h1, a1.y*Bv);
                h2 = fmaf(exp2x(a2.x*Av2), h2, a2.y*Bv);
                h3 = fmaf(exp2x(a3.x*Av3), h3, a3.y*Bv);
                pbc += DS;
            }
        }
    }
    size_t q0i = ((size_t)b*DI + d0)*CH + c, q1i = ((size_t)b*DI + d1)*CH + c;
    size_t q2i = ((size_t)b*DI + d2)*CH + c, q3i = ((size_t)b*DI + d3)*CH + c;
    Q[q0i*64 + lane] = h0; Q[q1i*64 + lane] = h1;
    Q[q2i*64 + lane] = h2; Q[q3i*64 + lane] = h3;
    float s0w = wsum64(ds0), s1w = wsum64(ds1), s2w = wsum64(ds2), s3w = wsum64(ds3);
    if (lane == 63){ S[q0i]=s0w; S[q1i]=s1w; S[q2i]=s2w; S[q3i]=s3w; }
}

// ======= chunked scan, pass C: 2 ch packed (pk_fma), interleaved P, XCD-swizzled, Yst out =======
__global__ __launch_bounds__(256) void scan_c(const unsigned int* __restrict__ UGt,
                       const unsigned short* __restrict__ DELtb,
                       const unsigned int* __restrict__ BCb,
                       const float* __restrict__ A_log,
                       const float* __restrict__ Dskip,
                       const float* __restrict__ Q,
                       const float* __restrict__ S,
                       unsigned short* __restrict__ Yb)
{
    __shared__ __align__(16) f32x2 Pr[4][4][66];    // [wave][step][state] interleaved {ch0,ch1}
    __shared__ float Ypark[4][2][4];
    __shared__ __align__(16) f32x4 dlb[4][64];      // [wave][step]={dl0,dl1,du0,du1}
    __shared__ unsigned short Yst[64][12];
    int tid = threadIdx.x;
    int wave = tid >> 6, lane = tid & 63;
    f32x2 (*PrW)[66] = Pr[wave];
    float* Yp0 = Ypark[wave][0];
    float* Yp1 = Ypark[wave][1];
    f32x4* DbW = dlb[wave];
    // XCD-bijective swizzle: grid = 4352 = 8*544. Adjacent logical blocks (adjacent dd,
    // same (b,c)) land on the SAME XCD so its L2 assembles full 64B lines from 8B pieces.
    int sb = (blockIdx.x & 7)*544 + (blockIdx.x >> 3);
    int wid = sb*4 + wave;                    // 4 waves share (b,c); dd consecutive
    int dd = wid % (DI/2);
    int c  = (wid / (DI/2)) % CH;
    int b  = wid / ((DI/2)*CH);
    int d0 = dd, d1 = dd + DI/2;
    int wid0 = sb*4;
    int dd0b = wid0 % (DI/2);
    int cB = (wid0 / (DI/2)) % CH;
    int bB = wid0 / ((DI/2)*CH);
    const float L2E = 1.44269504f;
    f32x2 Av;
    Av.x = -__expf(A_log[d0*DS + lane]) * L2E;
    Av.y = -__expf(A_log[d1*DS + lane]) * L2E;
    float Dd0 = Dskip[d0], Dd1 = Dskip[d1];
    size_t q0 = ((size_t)b*DI + d0)*CH, q1 = ((size_t)b*DI + d1)*CH;
    float h0=0.f, h1=0.f;
    for (int j=0; j<c; ++j){
        h0 = fmaf(exp2x(Av.x*S[q0+j]), h0, Q[(q0+j)*64 + lane]);
        h1 = fmaf(exp2x(Av.y*S[q1+j]), h1, Q[(q1+j)*64 + lane]);
    }
    f32x2 h; h.x = h0; h.y = h1;
    size_t tokBase = (size_t)b*LL + (size_t)c*TCH;
    size_t rb0 = ((size_t)b*DI + d0)*LL + c*TCH;
    size_t rb1 = ((size_t)b*DI + d1)*LL + c*TCH;
    int fr = lane >> 4, fq = (lane & 15)*4;
    for (int blk=0; blk<TCH/64; ++blk){
        size_t o0 = rb0 + blk*64 + lane, o1 = rb1 + blk*64 + lane;
        float dl0 = bfu2f(DELtb[o0]), dl1 = bfu2f(DELtb[o1]);
        unsigned int ug0 = UGt[o0], ug1 = UGt[o1];
        float ul0 = bfu2f((unsigned short)ug0), ul1 = bfu2f((unsigned short)ug1);
        float gl0 = bfu2f((unsigned short)(ug0 >> 16)), gl1 = bfu2f((unsigned short)(ug1 >> 16));
        DbW[lane] = (f32x4){dl0, dl1, dl0*ul0, dl1*ul1};
        float y0=0.f, y1=0.f;
        const unsigned int* pbc = BCb + (tokBase + blk*64)*DS;
        #pragma unroll 1
        for (int f=0; f<16; ++f){
            #pragma unroll
            for (int i=0; i<4; ++i){
                f32x4 dd4 = DbW[f*4 + i];      // uniform-address b128 broadcast
                unsigned int bc = pbc[lane];
                float Bv = bclo(bc);
                float Cv = bchi(bc);
                f32x2 t = pk_mul2(__builtin_shufflevector(dd4, dd4, 0, 1), Av);
                f32x2 e; e.x = exp2x(t.x); e.y = exp2x(t.y);
                f32x2 dub; dub.x = dd4.z*Bv; dub.y = dd4.w*Bv;
                h = pk_fma2(e, h, dub);
                f32x2 hc; hc.x = h.x*Cv; hc.y = h.y*Cv;
                PrW[i][lane] = hc;             // single ds_write_b64
                pbc += DS;
            }
            f32x4 qa = *(const f32x4*)&PrW[fr][fq];
            f32x4 qb = *(const f32x4*)&PrW[fr][fq+2];
            float s0f = (qa.x+qa.z)+(qb.x+qb.z);
            float s1f = (qa.y+qa.w)+(qb.y+qb.w);
            DPPADD(s0f,0x111); DPPADD(s0f,0x112); DPPADD(s0f,0x114); DPPADD(s0f,0x118);
            DPPADD(s1f,0x111); DPPADD(s1f,0x112); DPPADD(s1f,0x114); DPPADD(s1f,0x118);
            if ((lane & 15) == 15){ Yp0[fr] = s0f; Yp1[fr] = s1f; }
            float g0 = Yp0[lane & 3];
            float g1 = Yp1[lane & 3];
            if ((lane >> 2) == f){ y0 = g0; y1 = g1; }
        }
        Yst[lane][wave]     = f2bfu((y0 + ul0*Dd0)*gl0);
        Yst[lane][4 + wave] = f2bfu((y1 + ul1*Dd1)*gl1);
        __syncthreads();
        if (tid < 128){
            int row = tid & 63, grp = tid >> 6;
            ushort4 v = *(const ushort4*)&Yst[row][grp*4];
            size_t trow = (size_t)bB*LL + (size_t)cB*TCH + blk*64 + row;
            *(ushort4*)&Yb[trow*DI + dd0b + grp*(DI/2)] = v;
        }
        __syncthreads();
    }
}

// ------- weight f32 -> bf16 convert -------
__global__ __launch_bounds__(256) void wconv_kernel(const float* __restrict__ src,
                            unsigned short* __restrict__ dst,
                            int total, int kin, int kout)
{
    int idx = blockIdx.x*256 + threadIdx.x;
    if (idx >= total) return;
    int r = idx / kout, c = idx - r*kout;
    float v = (c < kin) ? src[(size_t)r*kin + c] : 0.f;
    dst[idx] = f2bfu(v);
}

// ------- head: two-stage mean-pool + regression -------
__global__ __launch_bounds__(256) void head1_kernel(const float* __restrict__ X,
                             float* __restrict__ Pt)
{
    int b = blockIdx.x >> 6, c = blockIdx.x & 63;
    int tid = threadIdx.x;
    for (int dm = tid; dm < DM; dm += 256){
        float s = 0.f;
        const float* base = X + ((size_t)b*LL + c*32)*DM + dm;
        #pragma unroll 8
        for (int tt=0; tt<32; ++tt) s += base[(size_t)tt*DM];
        Pt[(size_t)(b*64 + c)*DM + dm] = s;
    }
}

__global__ __launch_bounds__(256) void head2_kernel(const float* __restrict__ Pt,
                             const float* __restrict__ reg_w,
                             const float* __restrict__ reg_b,
                             float* __restrict__ out)
{
    __shared__ float feat[DM];
    int b = blockIdx.x, tid = threadIdx.x;
    for (int dm = tid; dm < DM; dm += 256){
        float s = 0.f;
        for (int c=0; c<64; ++c) s += Pt[(size_t)(b*64 + c)*DM + dm];
        float f = s * (1.0f/LL);
        feat[dm] = f;
        out[16 + b*DM + dm] = f;
    }
    __syncthreads();
    if (tid < NSC){
        float s = reg_b[tid];
        const float* wr = reg_w + tid*DM;
        for (int k=0;k<DM;++k) s = fmaf(feat[k], wr[k], s);
        out[b*NSC + tid] = s;
    }
}

extern "C" void kernel_launch(void* const* d_in, const int* in_sizes, int n_in,
                              void* d_out, int out_size, void* d_ws, size_t ws_size,
                              hipStream_t stream)
{
    const float* x_in  = (const float*)d_in[0];
    const float* ln_w  = (const float*)d_in[1];
    const float* ln_b  = (const float*)d_in[2];
    const float* Wi    = (const float*)d_in[3];
    const float* cw    = (const float*)d_in[4];
    const float* cb    = (const float*)d_in[5];
    const float* Wx    = (const float*)d_in[6];
    const float* Wdt   = (const float*)d_in[7];
    const float* bdt   = (const float*)d_in[8];
    const float* A_log = (const float*)d_in[9];
    const float* Dd    = (const float*)d_in[10];
    const float* Wo    = (const float*)d_in[11];
    const float* regw  = (const float*)d_in[12];
    const float* regb  = (const float*)d_in[13];
    float* out = (float*)d_out;

    char* base = (char*)d_ws;
    auto carve = [&](size_t bytes) -> char* {
        char* p = base; base += (bytes + 255) & ~(size_t)255; return p;
    };
    unsigned short* XZb   = (unsigned short*)carve((size_t)MTOK*1088*2);
    unsigned int*   UGt   = (unsigned int*)carve((size_t)MTOK*544*4);
    unsigned short* DELtb = (unsigned short*)carve((size_t)MTOK*544*2);
    float*          DTb   = (float*)carve((size_t)MTOK*DTR*4);
    unsigned int*   BCb   = (unsigned int*)carve((size_t)MTOK*DS*4);
    float*          Xb    = (float*)carve((size_t)MTOK*272*4);
    unsigned short* Yb    = (unsigned short*)carve((size_t)MTOK*544*2);
    char*           SCR   = carve((size_t)MTOK*272*4);   // Hb / XCb / Q / Pt overlay
    float*          Sbuf  = (float*)carve((size_t)BB*DI*CH*4);
    unsigned short* WiB   = (unsigned short*)carve((size_t)NL*1088*DM*2);
    unsigned short* WxB   = (unsigned short*)carve((size_t)NL*145*DI*2);
    unsigned short* WoB   = (unsigned short*)carve((size_t)NL*272*DI*2);

    unsigned short* Hb  = (unsigned short*)SCR;
    unsigned short* XCb = (unsigned short*)SCR;
    float*          Q   = (float*)SCR;
    float*          Pt  = (float*)SCR;

    (void)hipMemcpyAsync(Xb, x_in, sizeof(float)*(size_t)MTOK*DM, hipMemcpyDeviceToDevice, stream);

    wconv_kernel<<<(NL*1088*DM + 255)/256, 256, 0, stream>>>(Wi, WiB, NL*1088*DM, DM, DM);
    wconv_kernel<<<(NL*145*DI + 255)/256, 256, 0, stream>>>(Wx, WxB, NL*145*DI, DI, DI);
    wconv_kernel<<<(NL*272*DI + 255)/256, 256, 0, stream>>>(Wo, WoB, NL*272*DI, DI, DI);

    for (int l=0; l<NL; ++l){
        ln_kernel<<<MTOK/4, 256, 0, stream>>>(Xb, ln_w + l*DM, ln_b + l*DM, Hb);
        gmfma<1,false><<<dim3(MTOK/128, (2*DI+127)/128), 256, 0, stream>>>(
            Hb, DM, WiB + (size_t)l*2*DI*DM, DM, XZb, 2*DI, nullptr, 0, nullptr, 2*DI, DM);
        conv_t2_kernel<<<BB*256, 256, 0, stream>>>(XZb, cw + l*DI*4, cb + l*DI, UGt, XCb);
        gmfma<2,false><<<dim3(MTOK/128, 2), 256, 0, stream>>>(
            XCb, DI, WxB + (size_t)l*145*DI, DI, DTb, DTR, nullptr, 0, BCb, 145, DI);
        scan_a<<<(BB*CH*DQ)/4, 256, 0, stream>>>(UGt, DTb, BCb, Wdt + (size_t)l*DI*DTR, bdt + l*DI,
                                                 A_log + (size_t)l*DI*DS, Q, Sbuf, DELtb);
        scan_c<<<(BB*CH*(DI/2))/4, 256, 0, stream>>>(UGt, DELtb, BCb,
                                                     A_log + (size_t)l*DI*DS, Dd + l*DI, Q, Sbuf, Yb);
        gmfma<0,true><<<dim3(MTOK/128, 3), 256, 0, stream>>>(
            Yb, DI, WoB + (size_t)l*DM*DI, DI, Xb, DM, Xb, DM, nullptr, DM, DI);
    }
    head1_kernel<<<BB*64, 256, 0, stream>>>(Xb, Pt);
    head2_kernel<<<BB, 256, 0, stream>>>(Pt, regw, regb, out);
}